// Round 4
// baseline (328.070 us; speedup 1.0000x reference)
//
#include <hip/hip_runtime.h>
#include <math.h>

// LDR toep_corner via FFT chain, radix-16 registerized FFT (4096 = 16^3).
// out[j,b] = Re ifft( sum_{i,s} Gf_ijs . fft( D . fft( Hf_ijs . Xf_ib ) ) )
// Hf = fft(D.H), Xf = ifft(conj(D).x), Gf = fft(G), D_k = exp(i*pi*k/N).
//
// R4: ifft linearity -> each middle wg iffts its own partial and atomicAdds
// into out (P buffer and final kernel eliminated; ws = 8 MB).
// NS=2 ranks/wg, grid 1024. Single 32KB LDS buffer (R2-proven: occupancy
// beats barrier-count; R3's 64KB 2-buffer regressed 72->102us).

#define NFFT  4096
#define NT    256
#define CIN   4
#define COUT  4
#define RANK  4
#define BATCH 32
#define PI_F  3.14159265358979323846f

__device__ __forceinline__ float2 cmul(float2 a, float2 b) {
    return make_float2(a.x*b.x - a.y*b.y, a.x*b.y + a.y*b.x);
}
__device__ __forceinline__ float2 cadd(float2 a, float2 b){ return make_float2(a.x+b.x, a.y+b.y); }
__device__ __forceinline__ float2 csub(float2 a, float2 b){ return make_float2(a.x-b.x, a.y-b.y); }

// LDS bank swizzle (R2-proven: SQ_LDS_BANK_CONFLICT = 0).
__device__ __forceinline__ int SW(int e){ return e ^ ((e >> 4) & 15); }

// 16-point DFT in registers, natural order in/out (R2-proven numerics).
template<int SIGN>
__device__ __forceinline__ void dft16(float2 v[16]) {
    const float sgn = (float)SIGN;
    const float C8 = 0.923879532511287f, S8 = 0.382683432365090f, H2 = 0.707106781186548f;
    const float2 w1 = make_float2( C8,  sgn*S8);
    const float2 w2 = make_float2( H2,  sgn*H2);
    const float2 w3 = make_float2( S8,  sgn*C8);
    const float2 w4 = make_float2(0.f,  sgn);
    const float2 w6 = make_float2(-H2,  sgn*H2);
    const float2 w9 = make_float2(-C8, -sgn*S8);
    float2 t[16];
    #pragma unroll
    for (int p = 0; p < 4; ++p) {
        float2 a0 = v[p], a1 = v[p+4], a2 = v[p+8], a3 = v[p+12];
        float2 b0 = cadd(a0,a2), b1 = csub(a0,a2), b2 = cadd(a1,a3), b3 = csub(a1,a3);
        float2 ib3 = make_float2(-sgn*b3.y, sgn*b3.x);   // SIGN*i*b3
        float2 X0 = cadd(b0,b2), X2c = csub(b0,b2);
        float2 X1 = cadd(b1,ib3), X3 = csub(b1,ib3);
        if (p == 1) { X1 = cmul(X1,w1); X2c = cmul(X2c,w2); X3 = cmul(X3,w3); }
        else if (p == 2) { X1 = cmul(X1,w2); X2c = cmul(X2c,w4); X3 = cmul(X3,w6); }
        else if (p == 3) { X1 = cmul(X1,w3); X2c = cmul(X2c,w6); X3 = cmul(X3,w9); }
        t[4*p+0]=X0; t[4*p+1]=X1; t[4*p+2]=X2c; t[4*p+3]=X3;
    }
    #pragma unroll
    for (int q = 0; q < 4; ++q) {
        float2 a0 = t[q], a1 = t[q+4], a2 = t[q+8], a3 = t[q+12];
        float2 b0 = cadd(a0,a2), b1 = csub(a0,a2), b2 = cadd(a1,a3), b3 = csub(a1,a3);
        float2 ib3 = make_float2(-sgn*b3.y, sgn*b3.x);
        v[q+0]  = cadd(b0,b2);
        v[q+8]  = csub(b0,b2);
        v[q+4]  = cadd(b1,ib3);
        v[q+12] = csub(b1,ib3);
    }
}

// v[k] *= e^{i*k*ang}, incremental powers.
__device__ __forceinline__ void twiddle16(float2 v[16], float ang) {
    float sn, cs; __sincosf(ang, &sn, &cs);
    float2 w = make_float2(cs, sn), t = w;
    v[1] = cmul(v[1], t);
    #pragma unroll
    for (int k = 2; k < 16; ++k) { t = cmul(t, w); v[k] = cmul(v[k], t); }
}

// Stockham radix-16, 3 stages, single 32KB buffer, 4 barriers (R2-proven).
// Input: v[r] = x[tid + 256r]. Output: v[k] = X[tid + 256k].
// Entry assumes lds free; exits with trailing barrier (lds free again).
template<int SIGN>
__device__ void fft4096_r16(float2 v[16], float2* lds, int tid) {
    // Stage A: p=tid, s=1
    dft16<SIGN>(v);
    twiddle16(v, (float)SIGN * 2.0f * PI_F * (float)tid / 4096.0f);
    #pragma unroll
    for (int k = 0; k < 16; ++k) lds[SW(16*tid + k)] = v[k];
    __syncthreads();
    // Stage B: p=tid>>4, q=tid&15, s=16
    #pragma unroll
    for (int r = 0; r < 16; ++r) v[r] = lds[SW(tid + 256*r)];
    dft16<SIGN>(v);
    twiddle16(v, (float)SIGN * 2.0f * PI_F * (float)(tid >> 4) / 256.0f);
    __syncthreads();                       // in-place: all reads before any write
    {
        const int q = tid & 15, p = tid >> 4;
        #pragma unroll
        for (int k = 0; k < 16; ++k) lds[SW(q + 256*p + 16*k)] = v[k];
    }
    __syncthreads();
    // Stage C: s=256, no twiddle
    #pragma unroll
    for (int r = 0; r < 16; ++r) v[r] = lds[SW(tid + 256*r)];
    dft16<SIGN>(v);
    __syncthreads();                       // lds reusable by caller
}

// ---- Kernel A: precompute Hf (64 rows), Gf (64 rows), Xf (128 rows) ----
__global__ __launch_bounds__(NT, 2) void ldr_pre_k(
    const float* __restrict__ x, const float* __restrict__ G, const float* __restrict__ H,
    float2* __restrict__ Hf, float2* __restrict__ Gf, float2* __restrict__ Xf)
{
    __shared__ float2 lds[NFFT];
    const int tid = threadIdx.x;
    const int bid = blockIdx.x;
    float2 v[16];
    if (bid < 64) {
        const float* h = H + (size_t)bid * NFFT;
        float sn, cs; __sincosf(PI_F * (float)tid / (float)NFFT, &sn, &cs);
        float2 d = make_float2(cs, sn);
        const float2 dstep = make_float2(0.980785280403230449f, 0.195090322016128268f); // e^{i*pi/16}
        #pragma unroll
        for (int k = 0; k < 16; ++k) {
            float hv = h[tid + 256*k];
            v[k] = make_float2(d.x*hv, d.y*hv);
            d = cmul(d, dstep);
        }
        fft4096_r16<-1>(v, lds, tid);
        float2* o = Hf + (size_t)bid * NFFT;
        #pragma unroll
        for (int k = 0; k < 16; ++k) o[tid + 256*k] = v[k];
    } else if (bid < 128) {
        const int row = bid - 64;
        const float* g = G + (size_t)row * NFFT;
        #pragma unroll
        for (int k = 0; k < 16; ++k) v[k] = make_float2(g[tid + 256*k], 0.0f);
        fft4096_r16<-1>(v, lds, tid);
        float2* o = Gf + (size_t)row * NFFT;
        #pragma unroll
        for (int k = 0; k < 16; ++k) o[tid + 256*k] = v[k];
    } else {
        const int row = bid - 128;
        const float* xp = x + (size_t)row * NFFT;
        float sn, cs; __sincosf(PI_F * (float)tid / (float)NFFT, &sn, &cs);
        float2 d = make_float2(cs, -sn);                                                 // conj(D)
        const float2 dstep = make_float2(0.980785280403230449f, -0.195090322016128268f);
        #pragma unroll
        for (int k = 0; k < 16; ++k) {
            float xv = xp[tid + 256*k];
            v[k] = make_float2(d.x*xv, d.y*xv);
            d = cmul(d, dstep);
        }
        fft4096_r16<1>(v, lds, tid);
        const float invn = 1.0f / (float)NFFT;
        float2* o = Xf + (size_t)row * NFFT;
        #pragma unroll
        for (int k = 0; k < 16; ++k) o[tid + 256*k] = make_float2(v[k].x*invn, v[k].y*invn);
    }
}

// ---- Kernel B: middle+final fused. grid 1024, NS=2 ranks per wg.
// bid = ij*64 + b*2 + sg.  acc = sum_{s in sg} Gf . fft(D . fft(Hf . Xf));
// then w = unnorm_ifft(acc); atomicAdd(out[j,b], w.x / N).  Valid because
// ifft is linear: sum of per-partial iffts == ifft of the sum.
__global__ __launch_bounds__(NT, 4) void ldr_mid_k(
    const float2* __restrict__ Hf, const float2* __restrict__ Xf,
    const float2* __restrict__ Gf, float* __restrict__ out)
{
    __shared__ float2 lds[NFFT];
    const int tid = threadIdx.x;
    const int bid = blockIdx.x;
    const int sg  = bid & 1;
    const int b   = (bid >> 1) & (BATCH - 1);
    const int ij  = bid >> 6;
    const int i   = ij >> 2;          // COUT = 4
    const int j   = ij & 3;
    const float2* xrow = Xf + (size_t)(i*BATCH + b) * NFFT;

    float2 acc[16];
    #pragma unroll
    for (int k = 0; k < 16; ++k) acc[k] = make_float2(0.0f, 0.0f);

    for (int ss = 0; ss < 2; ++ss) {
        const int s = sg*2 + ss;
        const float2* hrow = Hf + (size_t)(ij*RANK + s) * NFFT;
        const float2* grow = Gf + (size_t)(ij*RANK + s) * NFFT;
        float2 v[16];
        #pragma unroll
        for (int k = 0; k < 16; ++k) {
            const int e = tid + 256*k;
            v[k] = cmul(hrow[e], xrow[e]);
        }
        fft4096_r16<-1>(v, lds, tid);
        // multiply by D in registers: elem e = tid + 256k, D_e = e^{i*pi*e/N}
        float sn, cs; __sincosf(PI_F * (float)tid / (float)NFFT, &sn, &cs);
        float2 d = make_float2(cs, sn);
        const float2 dstep = make_float2(0.980785280403230449f, 0.195090322016128268f);
        #pragma unroll
        for (int k = 0; k < 16; ++k) { v[k] = cmul(v[k], d); d = cmul(d, dstep); }
        fft4096_r16<-1>(v, lds, tid);
        #pragma unroll
        for (int k = 0; k < 16; ++k) {
            const int e = tid + 256*k;
            acc[k] = cadd(acc[k], cmul(grow[e], v[k]));
        }
    }
    // partial inverse transform + accumulate into out
    fft4096_r16<1>(acc, lds, tid);
    const float invn = 1.0f / (float)NFFT;
    float* orow = out + (size_t)(j*BATCH + b) * NFFT;
    #pragma unroll
    for (int k = 0; k < 16; ++k)
        atomicAdd(&orow[tid + 256*k], acc[k].x * invn);
}

extern "C" void kernel_launch(void* const* d_in, const int* in_sizes, int n_in,
                              void* d_out, int out_size, void* d_ws, size_t ws_size,
                              hipStream_t stream) {
    const float* x = (const float*)d_in[0];   // (CIN, B, N)
    const float* G = (const float*)d_in[1];   // (CIN, COUT, R, N)
    const float* H = (const float*)d_in[2];   // (CIN, COUT, R, N)
    float* out = (float*)d_out;               // (COUT, B, N)

    float2* Hf = (float2*)d_ws;                    // 64 rows  (2 MB)
    float2* Gf = Hf + (size_t)64 * NFFT;           // 64 rows  (2 MB)
    float2* Xf = Gf + (size_t)64 * NFFT;           // 128 rows (4 MB)

    // zero out for atomic accumulation (d_out is poisoned before every launch)
    hipMemsetAsync(d_out, 0, (size_t)out_size * sizeof(float), stream);

    ldr_pre_k<<<256, NT, 0, stream>>>(x, G, H, Hf, Gf, Xf);
    ldr_mid_k<<<CIN * COUT * BATCH * 2, NT, 0, stream>>>(Hf, Xf, Gf, out);
}

// Round 5
// 327.113 us; speedup vs baseline: 1.0029x; 1.0029x over previous
//
#include <hip/hip_runtime.h>
#include <math.h>

// LDR toep_corner via FFT chain, radix-16 registerized FFT (4096 = 16^3).
// out[j,b] = Re ifft( sum_{i,s} Gf_ijs . fft( D . fft( Hf_ijs . Xf_ib ) ) )
// Hf = fft(D.H), Xf = ifft(conj(D).x), Gf = fft(G), D_k = exp(i*pi*k/N).
//
// R5: ifft linearity (R4 idea) WITHOUT atomics (R4's 8.4M global fp32 atomics
// caused 700 MB of HBM RMW traffic, 266us). Each middle wg iffts its partial
// and stores the REAL part to a disjoint P plane (16 MB total); a trivially
// coalesced sum kernel reduces 8 planes -> out. Single 32KB LDS buffer,
// grid 1024 = 4 blocks/CU (R2-proven: occupancy beats barrier count).

#define NFFT  4096
#define NT    256
#define CIN   4
#define COUT  4
#define RANK  4
#define BATCH 32
#define PI_F  3.14159265358979323846f

__device__ __forceinline__ float2 cmul(float2 a, float2 b) {
    return make_float2(a.x*b.x - a.y*b.y, a.x*b.y + a.y*b.x);
}
__device__ __forceinline__ float2 cadd(float2 a, float2 b){ return make_float2(a.x+b.x, a.y+b.y); }
__device__ __forceinline__ float2 csub(float2 a, float2 b){ return make_float2(a.x-b.x, a.y-b.y); }

// LDS bank swizzle (R2-proven: SQ_LDS_BANK_CONFLICT = 0).
__device__ __forceinline__ int SW(int e){ return e ^ ((e >> 4) & 15); }

// 16-point DFT in registers, natural order in/out (R2-proven numerics).
template<int SIGN>
__device__ __forceinline__ void dft16(float2 v[16]) {
    const float sgn = (float)SIGN;
    const float C8 = 0.923879532511287f, S8 = 0.382683432365090f, H2 = 0.707106781186548f;
    const float2 w1 = make_float2( C8,  sgn*S8);
    const float2 w2 = make_float2( H2,  sgn*H2);
    const float2 w3 = make_float2( S8,  sgn*C8);
    const float2 w4 = make_float2(0.f,  sgn);
    const float2 w6 = make_float2(-H2,  sgn*H2);
    const float2 w9 = make_float2(-C8, -sgn*S8);
    float2 t[16];
    #pragma unroll
    for (int p = 0; p < 4; ++p) {
        float2 a0 = v[p], a1 = v[p+4], a2 = v[p+8], a3 = v[p+12];
        float2 b0 = cadd(a0,a2), b1 = csub(a0,a2), b2 = cadd(a1,a3), b3 = csub(a1,a3);
        float2 ib3 = make_float2(-sgn*b3.y, sgn*b3.x);   // SIGN*i*b3
        float2 X0 = cadd(b0,b2), X2c = csub(b0,b2);
        float2 X1 = cadd(b1,ib3), X3 = csub(b1,ib3);
        if (p == 1) { X1 = cmul(X1,w1); X2c = cmul(X2c,w2); X3 = cmul(X3,w3); }
        else if (p == 2) { X1 = cmul(X1,w2); X2c = cmul(X2c,w4); X3 = cmul(X3,w6); }
        else if (p == 3) { X1 = cmul(X1,w3); X2c = cmul(X2c,w6); X3 = cmul(X3,w9); }
        t[4*p+0]=X0; t[4*p+1]=X1; t[4*p+2]=X2c; t[4*p+3]=X3;
    }
    #pragma unroll
    for (int q = 0; q < 4; ++q) {
        float2 a0 = t[q], a1 = t[q+4], a2 = t[q+8], a3 = t[q+12];
        float2 b0 = cadd(a0,a2), b1 = csub(a0,a2), b2 = cadd(a1,a3), b3 = csub(a1,a3);
        float2 ib3 = make_float2(-sgn*b3.y, sgn*b3.x);
        v[q+0]  = cadd(b0,b2);
        v[q+8]  = csub(b0,b2);
        v[q+4]  = cadd(b1,ib3);
        v[q+12] = csub(b1,ib3);
    }
}

// v[k] *= e^{i*k*ang}, incremental powers.
__device__ __forceinline__ void twiddle16(float2 v[16], float ang) {
    float sn, cs; __sincosf(ang, &sn, &cs);
    float2 w = make_float2(cs, sn), t = w;
    v[1] = cmul(v[1], t);
    #pragma unroll
    for (int k = 2; k < 16; ++k) { t = cmul(t, w); v[k] = cmul(v[k], t); }
}

// Stockham radix-16, 3 stages, single 32KB buffer, 4 barriers (R2-proven).
// Input: v[r] = x[tid + 256r]. Output: v[k] = X[tid + 256k].
template<int SIGN>
__device__ void fft4096_r16(float2 v[16], float2* lds, int tid) {
    dft16<SIGN>(v);
    twiddle16(v, (float)SIGN * 2.0f * PI_F * (float)tid / 4096.0f);
    #pragma unroll
    for (int k = 0; k < 16; ++k) lds[SW(16*tid + k)] = v[k];
    __syncthreads();
    #pragma unroll
    for (int r = 0; r < 16; ++r) v[r] = lds[SW(tid + 256*r)];
    dft16<SIGN>(v);
    twiddle16(v, (float)SIGN * 2.0f * PI_F * (float)(tid >> 4) / 256.0f);
    __syncthreads();                       // in-place: all reads before any write
    {
        const int q = tid & 15, p = tid >> 4;
        #pragma unroll
        for (int k = 0; k < 16; ++k) lds[SW(q + 256*p + 16*k)] = v[k];
    }
    __syncthreads();
    #pragma unroll
    for (int r = 0; r < 16; ++r) v[r] = lds[SW(tid + 256*r)];
    dft16<SIGN>(v);
    __syncthreads();                       // lds reusable by caller
}

// ---- Kernel A: precompute Hf (64 rows), Gf (64 rows), Xf (128 rows) ----
__global__ __launch_bounds__(NT, 2) void ldr_pre_k(
    const float* __restrict__ x, const float* __restrict__ G, const float* __restrict__ H,
    float2* __restrict__ Hf, float2* __restrict__ Gf, float2* __restrict__ Xf)
{
    __shared__ float2 lds[NFFT];
    const int tid = threadIdx.x;
    const int bid = blockIdx.x;
    float2 v[16];
    if (bid < 64) {
        const float* h = H + (size_t)bid * NFFT;
        float sn, cs; __sincosf(PI_F * (float)tid / (float)NFFT, &sn, &cs);
        float2 d = make_float2(cs, sn);
        const float2 dstep = make_float2(0.980785280403230449f, 0.195090322016128268f); // e^{i*pi/16}
        #pragma unroll
        for (int k = 0; k < 16; ++k) {
            float hv = h[tid + 256*k];
            v[k] = make_float2(d.x*hv, d.y*hv);
            d = cmul(d, dstep);
        }
        fft4096_r16<-1>(v, lds, tid);
        float2* o = Hf + (size_t)bid * NFFT;
        #pragma unroll
        for (int k = 0; k < 16; ++k) o[tid + 256*k] = v[k];
    } else if (bid < 128) {
        const int row = bid - 64;
        const float* g = G + (size_t)row * NFFT;
        #pragma unroll
        for (int k = 0; k < 16; ++k) v[k] = make_float2(g[tid + 256*k], 0.0f);
        fft4096_r16<-1>(v, lds, tid);
        float2* o = Gf + (size_t)row * NFFT;
        #pragma unroll
        for (int k = 0; k < 16; ++k) o[tid + 256*k] = v[k];
    } else {
        const int row = bid - 128;
        const float* xp = x + (size_t)row * NFFT;
        float sn, cs; __sincosf(PI_F * (float)tid / (float)NFFT, &sn, &cs);
        float2 d = make_float2(cs, -sn);                                                 // conj(D)
        const float2 dstep = make_float2(0.980785280403230449f, -0.195090322016128268f);
        #pragma unroll
        for (int k = 0; k < 16; ++k) {
            float xv = xp[tid + 256*k];
            v[k] = make_float2(d.x*xv, d.y*xv);
            d = cmul(d, dstep);
        }
        fft4096_r16<1>(v, lds, tid);
        const float invn = 1.0f / (float)NFFT;
        float2* o = Xf + (size_t)row * NFFT;
        #pragma unroll
        for (int k = 0; k < 16; ++k) o[tid + 256*k] = make_float2(v[k].x*invn, v[k].y*invn);
    }
}

// ---- Kernel B: middle. grid 1024, NS=2 ranks/wg, per-partial ifft,
// real part stored to disjoint plane.  bid = ij*64 + b*2 + sg.
// Pr plane index p = i*2 + sg; Pr[((p*COUT + j)*BATCH + b)][n].
__global__ __launch_bounds__(NT, 4) void ldr_mid_k(
    const float2* __restrict__ Hf, const float2* __restrict__ Xf,
    const float2* __restrict__ Gf, float* __restrict__ Pr)
{
    __shared__ float2 lds[NFFT];
    const int tid = threadIdx.x;
    const int bid = blockIdx.x;
    const int sg  = bid & 1;
    const int b   = (bid >> 1) & (BATCH - 1);
    const int ij  = bid >> 6;
    const int i   = ij >> 2;          // COUT = 4
    const int j   = ij & 3;
    const float2* xrow = Xf + (size_t)(i*BATCH + b) * NFFT;

    float2 acc[16];
    #pragma unroll
    for (int k = 0; k < 16; ++k) acc[k] = make_float2(0.0f, 0.0f);

    for (int ss = 0; ss < 2; ++ss) {
        const int s = sg*2 + ss;
        const float2* hrow = Hf + (size_t)(ij*RANK + s) * NFFT;
        const float2* grow = Gf + (size_t)(ij*RANK + s) * NFFT;
        float2 v[16];
        #pragma unroll
        for (int k = 0; k < 16; ++k) {
            const int e = tid + 256*k;
            v[k] = cmul(hrow[e], xrow[e]);
        }
        fft4096_r16<-1>(v, lds, tid);
        // multiply by D in registers: elem e = tid + 256k, D_e = e^{i*pi*e/N}
        float sn, cs; __sincosf(PI_F * (float)tid / (float)NFFT, &sn, &cs);
        float2 d = make_float2(cs, sn);
        const float2 dstep = make_float2(0.980785280403230449f, 0.195090322016128268f);
        #pragma unroll
        for (int k = 0; k < 16; ++k) { v[k] = cmul(v[k], d); d = cmul(d, dstep); }
        fft4096_r16<-1>(v, lds, tid);
        #pragma unroll
        for (int k = 0; k < 16; ++k) {
            const int e = tid + 256*k;
            acc[k] = cadd(acc[k], cmul(grow[e], v[k]));
        }
    }
    // partial inverse transform; real part only (ifft linearity)
    fft4096_r16<1>(acc, lds, tid);
    const float invn = 1.0f / (float)NFFT;
    float* prow = Pr + (size_t)(((i*2 + sg)*COUT + j)*BATCH + b) * NFFT;
    #pragma unroll
    for (int k = 0; k < 16; ++k) prow[tid + 256*k] = acc[k].x * invn;
}

// ---- Kernel C: elementwise sum of 8 planes. out[jb][n] = sum_p Pr[p][jb][n].
// 131072 float4 elements, grid 512 x 256 threads, fully coalesced.
__global__ __launch_bounds__(NT, 4) void ldr_sum_k(
    const float4* __restrict__ Pr, float4* __restrict__ out)
{
    const int idx = blockIdx.x * NT + threadIdx.x;          // [0, 131072)
    const size_t plane = (size_t)(COUT * BATCH) * NFFT / 4; // float4 stride
    float4 a = Pr[idx];
    #pragma unroll
    for (int p = 1; p < 8; ++p) {
        float4 t = Pr[idx + (size_t)p * plane];
        a.x += t.x; a.y += t.y; a.z += t.z; a.w += t.w;
    }
    out[idx] = a;
}

extern "C" void kernel_launch(void* const* d_in, const int* in_sizes, int n_in,
                              void* d_out, int out_size, void* d_ws, size_t ws_size,
                              hipStream_t stream) {
    const float* x = (const float*)d_in[0];   // (CIN, B, N)
    const float* G = (const float*)d_in[1];   // (CIN, COUT, R, N)
    const float* H = (const float*)d_in[2];   // (CIN, COUT, R, N)
    float* out = (float*)d_out;               // (COUT, B, N)

    float2* Hf = (float2*)d_ws;                    // 64 rows  (2 MB)
    float2* Gf = Hf + (size_t)64 * NFFT;           // 64 rows  (2 MB)
    float2* Xf = Gf + (size_t)64 * NFFT;           // 128 rows (4 MB)
    float*  Pr = (float*)(Xf + (size_t)128 * NFFT); // 8 planes x 128 x 4096 fp32 (16 MB)

    ldr_pre_k<<<256, NT, 0, stream>>>(x, G, H, Hf, Gf, Xf);
    ldr_mid_k<<<CIN * COUT * BATCH * 2, NT, 0, stream>>>(Hf, Xf, Gf, Pr);
    ldr_sum_k<<<(COUT * BATCH * NFFT / 4) / NT, NT, 0, stream>>>((const float4*)Pr, (float4*)out);
}

// Round 7
// 108.905 us; speedup vs baseline: 3.0124x; 3.0037x over previous
//
#include <hip/hip_runtime.h>
#include <math.h>

// LDR toep_corner via FFT chain, radix-16 registerized FFT (4096 = 16^3).
// out[j,b] = Re ifft( sum_{i,s} Gf_ijs . fft( D . fft( Hf_ijs . Xf_ib ) ) )
// Hf = fft(D.H), Xf = ifft(conj(D).x), Gf = fft(G), D_k = exp(i*pi*k/N).
//
// R7 = R6 with the plane-index bug fixed (R6 wrote to plane is_=(ij*R+s)
// in [0,64) while the sum kernel read planes [0,16); correct plane is
// p = i*RANK + s). R6's spill theory still untested -> unchanged otherwise:
// NS=1 (no persistent acc), launch_bounds(256,2) (VGPR cap 256, no spill),
// 16 real partial planes + coalesced sum.

#define NFFT  4096
#define NT    256
#define CIN   4
#define COUT  4
#define RANK  4
#define BATCH 32
#define PI_F  3.14159265358979323846f

__device__ __forceinline__ float2 cmul(float2 a, float2 b) {
    return make_float2(a.x*b.x - a.y*b.y, a.x*b.y + a.y*b.x);
}
__device__ __forceinline__ float2 cadd(float2 a, float2 b){ return make_float2(a.x+b.x, a.y+b.y); }
__device__ __forceinline__ float2 csub(float2 a, float2 b){ return make_float2(a.x-b.x, a.y-b.y); }

// LDS bank swizzle (R2-proven: SQ_LDS_BANK_CONFLICT = 0).
__device__ __forceinline__ int SW(int e){ return e ^ ((e >> 4) & 15); }

// 16-point DFT in registers, natural order in/out (R2-proven numerics).
template<int SIGN>
__device__ __forceinline__ void dft16(float2 v[16]) {
    const float sgn = (float)SIGN;
    const float C8 = 0.923879532511287f, S8 = 0.382683432365090f, H2 = 0.707106781186548f;
    const float2 w1 = make_float2( C8,  sgn*S8);
    const float2 w2 = make_float2( H2,  sgn*H2);
    const float2 w3 = make_float2( S8,  sgn*C8);
    const float2 w4 = make_float2(0.f,  sgn);
    const float2 w6 = make_float2(-H2,  sgn*H2);
    const float2 w9 = make_float2(-C8, -sgn*S8);
    float2 t[16];
    #pragma unroll
    for (int p = 0; p < 4; ++p) {
        float2 a0 = v[p], a1 = v[p+4], a2 = v[p+8], a3 = v[p+12];
        float2 b0 = cadd(a0,a2), b1 = csub(a0,a2), b2 = cadd(a1,a3), b3 = csub(a1,a3);
        float2 ib3 = make_float2(-sgn*b3.y, sgn*b3.x);   // SIGN*i*b3
        float2 X0 = cadd(b0,b2), X2c = csub(b0,b2);
        float2 X1 = cadd(b1,ib3), X3 = csub(b1,ib3);
        if (p == 1) { X1 = cmul(X1,w1); X2c = cmul(X2c,w2); X3 = cmul(X3,w3); }
        else if (p == 2) { X1 = cmul(X1,w2); X2c = cmul(X2c,w4); X3 = cmul(X3,w6); }
        else if (p == 3) { X1 = cmul(X1,w3); X2c = cmul(X2c,w6); X3 = cmul(X3,w9); }
        t[4*p+0]=X0; t[4*p+1]=X1; t[4*p+2]=X2c; t[4*p+3]=X3;
    }
    #pragma unroll
    for (int q = 0; q < 4; ++q) {
        float2 a0 = t[q], a1 = t[q+4], a2 = t[q+8], a3 = t[q+12];
        float2 b0 = cadd(a0,a2), b1 = csub(a0,a2), b2 = cadd(a1,a3), b3 = csub(a1,a3);
        float2 ib3 = make_float2(-sgn*b3.y, sgn*b3.x);
        v[q+0]  = cadd(b0,b2);
        v[q+8]  = csub(b0,b2);
        v[q+4]  = cadd(b1,ib3);
        v[q+12] = csub(b1,ib3);
    }
}

// v[k] *= e^{i*k*ang}, incremental powers.
__device__ __forceinline__ void twiddle16(float2 v[16], float ang) {
    float sn, cs; __sincosf(ang, &sn, &cs);
    float2 w = make_float2(cs, sn), t = w;
    v[1] = cmul(v[1], t);
    #pragma unroll
    for (int k = 2; k < 16; ++k) { t = cmul(t, w); v[k] = cmul(v[k], t); }
}

// Stockham radix-16, 3 stages, single 32KB buffer, 4 barriers (R2-proven).
// Input: v[r] = x[tid + 256r]. Output: v[k] = X[tid + 256k].
template<int SIGN>
__device__ void fft4096_r16(float2 v[16], float2* lds, int tid) {
    dft16<SIGN>(v);
    twiddle16(v, (float)SIGN * 2.0f * PI_F * (float)tid / 4096.0f);
    #pragma unroll
    for (int k = 0; k < 16; ++k) lds[SW(16*tid + k)] = v[k];
    __syncthreads();
    #pragma unroll
    for (int r = 0; r < 16; ++r) v[r] = lds[SW(tid + 256*r)];
    dft16<SIGN>(v);
    twiddle16(v, (float)SIGN * 2.0f * PI_F * (float)(tid >> 4) / 256.0f);
    __syncthreads();                       // in-place: all reads before any write
    {
        const int q = tid & 15, p = tid >> 4;
        #pragma unroll
        for (int k = 0; k < 16; ++k) lds[SW(q + 256*p + 16*k)] = v[k];
    }
    __syncthreads();
    #pragma unroll
    for (int r = 0; r < 16; ++r) v[r] = lds[SW(tid + 256*r)];
    dft16<SIGN>(v);
    __syncthreads();                       // lds reusable by caller
}

// ---- Kernel A: precompute Hf (64 rows), Gf (64 rows), Xf (128 rows) ----
__global__ __launch_bounds__(NT, 2) void ldr_pre_k(
    const float* __restrict__ x, const float* __restrict__ G, const float* __restrict__ H,
    float2* __restrict__ Hf, float2* __restrict__ Gf, float2* __restrict__ Xf)
{
    __shared__ float2 lds[NFFT];
    const int tid = threadIdx.x;
    const int bid = blockIdx.x;
    float2 v[16];
    if (bid < 64) {
        const float* h = H + (size_t)bid * NFFT;
        float sn, cs; __sincosf(PI_F * (float)tid / (float)NFFT, &sn, &cs);
        float2 d = make_float2(cs, sn);
        const float2 dstep = make_float2(0.980785280403230449f, 0.195090322016128268f); // e^{i*pi/16}
        #pragma unroll
        for (int k = 0; k < 16; ++k) {
            float hv = h[tid + 256*k];
            v[k] = make_float2(d.x*hv, d.y*hv);
            d = cmul(d, dstep);
        }
        fft4096_r16<-1>(v, lds, tid);
        float2* o = Hf + (size_t)bid * NFFT;
        #pragma unroll
        for (int k = 0; k < 16; ++k) o[tid + 256*k] = v[k];
    } else if (bid < 128) {
        const int row = bid - 64;
        const float* g = G + (size_t)row * NFFT;
        #pragma unroll
        for (int k = 0; k < 16; ++k) v[k] = make_float2(g[tid + 256*k], 0.0f);
        fft4096_r16<-1>(v, lds, tid);
        float2* o = Gf + (size_t)row * NFFT;
        #pragma unroll
        for (int k = 0; k < 16; ++k) o[tid + 256*k] = v[k];
    } else {
        const int row = bid - 128;
        const float* xp = x + (size_t)row * NFFT;
        float sn, cs; __sincosf(PI_F * (float)tid / (float)NFFT, &sn, &cs);
        float2 d = make_float2(cs, -sn);                                                 // conj(D)
        const float2 dstep = make_float2(0.980785280403230449f, -0.195090322016128268f);
        #pragma unroll
        for (int k = 0; k < 16; ++k) {
            float xv = xp[tid + 256*k];
            v[k] = make_float2(d.x*xv, d.y*xv);
            d = cmul(d, dstep);
        }
        fft4096_r16<1>(v, lds, tid);
        const float invn = 1.0f / (float)NFFT;
        float2* o = Xf + (size_t)row * NFFT;
        #pragma unroll
        for (int k = 0; k < 16; ++k) o[tid + 256*k] = make_float2(v[k].x*invn, v[k].y*invn);
    }
}

// ---- Kernel B: middle. grid 2048 = ij(16) x s(4) x b(32); one rank per wg,
// no accumulator registers. bid = (ij*RANK + s)*BATCH + b (consecutive bids
// share hrow/grow -> L2 locality). Partial real ifft output to plane
// p = i*RANK + s (16 planes): Pr[((p*COUT + j)*BATCH + b)][n].
__global__ __launch_bounds__(NT, 2) void ldr_mid_k(
    const float2* __restrict__ Hf, const float2* __restrict__ Xf,
    const float2* __restrict__ Gf, float* __restrict__ Pr)
{
    __shared__ float2 lds[NFFT];
    const int tid = threadIdx.x;
    const int bid = blockIdx.x;
    const int b   = bid & (BATCH - 1);
    const int is_ = bid >> 5;           // ij*RANK + s  (row index into Hf/Gf)
    const int s   = is_ & 3;
    const int ij  = is_ >> 2;
    const int i   = ij >> 2;            // COUT = 4
    const int j   = ij & 3;
    const float2* xrow = Xf + (size_t)(i*BATCH + b) * NFFT;
    const float2* hrow = Hf + (size_t)is_ * NFFT;
    const float2* grow = Gf + (size_t)is_ * NFFT;

    float2 v[16];
    #pragma unroll
    for (int k = 0; k < 16; ++k) {
        const int e = tid + 256*k;
        v[k] = cmul(hrow[e], xrow[e]);
    }
    fft4096_r16<-1>(v, lds, tid);
    // multiply by D in registers: elem e = tid + 256k, D_e = e^{i*pi*e/N}
    {
        float sn, cs; __sincosf(PI_F * (float)tid / (float)NFFT, &sn, &cs);
        float2 d = make_float2(cs, sn);
        const float2 dstep = make_float2(0.980785280403230449f, 0.195090322016128268f);
        #pragma unroll
        for (int k = 0; k < 16; ++k) { v[k] = cmul(v[k], d); d = cmul(d, dstep); }
    }
    fft4096_r16<-1>(v, lds, tid);
    #pragma unroll
    for (int k = 0; k < 16; ++k)
        v[k] = cmul(grow[tid + 256*k], v[k]);
    // partial inverse transform; real part only (ifft linearity)
    fft4096_r16<1>(v, lds, tid);
    const float invn = 1.0f / (float)NFFT;
    const int p = i * RANK + s;         // FIXED: plane in [0,16), was is_ in [0,64)
    float* prow = Pr + (size_t)((p*COUT + j)*BATCH + b) * NFFT;
    #pragma unroll
    for (int k = 0; k < 16; ++k) prow[tid + 256*k] = v[k].x * invn;
}

// ---- Kernel C: elementwise sum of 16 planes. out[jb][n] = sum_p Pr[p][jb][n].
// 131072 float4 elements, grid 512 x 256 threads, fully coalesced.
__global__ __launch_bounds__(NT, 4) void ldr_sum_k(
    const float4* __restrict__ Pr, float4* __restrict__ out)
{
    const int idx = blockIdx.x * NT + threadIdx.x;          // [0, 131072)
    const size_t plane = (size_t)(COUT * BATCH) * NFFT / 4; // float4 stride
    float4 a = Pr[idx];
    #pragma unroll
    for (int p = 1; p < 16; ++p) {
        float4 t = Pr[idx + (size_t)p * plane];
        a.x += t.x; a.y += t.y; a.z += t.z; a.w += t.w;
    }
    out[idx] = a;
}

extern "C" void kernel_launch(void* const* d_in, const int* in_sizes, int n_in,
                              void* d_out, int out_size, void* d_ws, size_t ws_size,
                              hipStream_t stream) {
    const float* x = (const float*)d_in[0];   // (CIN, B, N)
    const float* G = (const float*)d_in[1];   // (CIN, COUT, R, N)
    const float* H = (const float*)d_in[2];   // (CIN, COUT, R, N)
    float* out = (float*)d_out;               // (COUT, B, N)

    float2* Hf = (float2*)d_ws;                     // 64 rows  (2 MB)
    float2* Gf = Hf + (size_t)64 * NFFT;            // 64 rows  (2 MB)
    float2* Xf = Gf + (size_t)64 * NFFT;            // 128 rows (4 MB)
    float*  Pr = (float*)(Xf + (size_t)128 * NFFT); // 16 planes x 128 x 4096 fp32 (32 MB)

    ldr_pre_k<<<256, NT, 0, stream>>>(x, G, H, Hf, Gf, Xf);
    ldr_mid_k<<<CIN * COUT * RANK * BATCH, NT, 0, stream>>>(Hf, Xf, Gf, Pr);
    ldr_sum_k<<<(COUT * BATCH * NFFT / 4) / NT, NT, 0, stream>>>((const float4*)Pr, (float4*)out);
}

// Round 8
// 108.441 us; speedup vs baseline: 3.0253x; 1.0043x over previous
//
#include <hip/hip_runtime.h>
#include <math.h>

// LDR toep_corner via FFT chain, radix-16 registerized FFT (4096 = 16^3).
// out[j,b] = Re ifft( sum_{i,s} Gf_ijs . fft( D . fft( Hf_ijs . Xf_ib ) ) )
// Hf = fft(D.H), Xf = ifft(conj(D).x), Gf = fft(G), D_k = exp(i*pi*k/N).
//
// R8: each rank-unit's time-domain partial is REAL (real matrix x real vector)
// => its spectrum Y is conjugate-symmetric. Mid drops its 3rd (inverse) FFT
// and stores only the half-spectrum k=0..2047 (DC & Nyquist, both real, packed
// into element 0). Final sums 16 half-rows per (j,b), mirrors the upper half,
// does ONE ifft, writes real output. FFT count 6144 -> 4224 (-31%).
// R7 lessons kept: NS=1 (no acc regs), launch_bounds(256,2) (no spill,
// VGPR~108), 32KB single-buffer FFT, XOR bank swizzle.

#define NFFT  4096
#define NT    256
#define CIN   4
#define COUT  4
#define RANK  4
#define BATCH 32
#define PI_F  3.14159265358979323846f

__device__ __forceinline__ float2 cmul(float2 a, float2 b) {
    return make_float2(a.x*b.x - a.y*b.y, a.x*b.y + a.y*b.x);
}
__device__ __forceinline__ float2 cadd(float2 a, float2 b){ return make_float2(a.x+b.x, a.y+b.y); }
__device__ __forceinline__ float2 csub(float2 a, float2 b){ return make_float2(a.x-b.x, a.y-b.y); }

// LDS bank swizzle (R2-proven: SQ_LDS_BANK_CONFLICT ~ 0).
__device__ __forceinline__ int SW(int e){ return e ^ ((e >> 4) & 15); }

// 16-point DFT in registers, natural order in/out (R2-proven numerics).
template<int SIGN>
__device__ __forceinline__ void dft16(float2 v[16]) {
    const float sgn = (float)SIGN;
    const float C8 = 0.923879532511287f, S8 = 0.382683432365090f, H2 = 0.707106781186548f;
    const float2 w1 = make_float2( C8,  sgn*S8);
    const float2 w2 = make_float2( H2,  sgn*H2);
    const float2 w3 = make_float2( S8,  sgn*C8);
    const float2 w4 = make_float2(0.f,  sgn);
    const float2 w6 = make_float2(-H2,  sgn*H2);
    const float2 w9 = make_float2(-C8, -sgn*S8);
    float2 t[16];
    #pragma unroll
    for (int p = 0; p < 4; ++p) {
        float2 a0 = v[p], a1 = v[p+4], a2 = v[p+8], a3 = v[p+12];
        float2 b0 = cadd(a0,a2), b1 = csub(a0,a2), b2 = cadd(a1,a3), b3 = csub(a1,a3);
        float2 ib3 = make_float2(-sgn*b3.y, sgn*b3.x);   // SIGN*i*b3
        float2 X0 = cadd(b0,b2), X2c = csub(b0,b2);
        float2 X1 = cadd(b1,ib3), X3 = csub(b1,ib3);
        if (p == 1) { X1 = cmul(X1,w1); X2c = cmul(X2c,w2); X3 = cmul(X3,w3); }
        else if (p == 2) { X1 = cmul(X1,w2); X2c = cmul(X2c,w4); X3 = cmul(X3,w6); }
        else if (p == 3) { X1 = cmul(X1,w3); X2c = cmul(X2c,w6); X3 = cmul(X3,w9); }
        t[4*p+0]=X0; t[4*p+1]=X1; t[4*p+2]=X2c; t[4*p+3]=X3;
    }
    #pragma unroll
    for (int q = 0; q < 4; ++q) {
        float2 a0 = t[q], a1 = t[q+4], a2 = t[q+8], a3 = t[q+12];
        float2 b0 = cadd(a0,a2), b1 = csub(a0,a2), b2 = cadd(a1,a3), b3 = csub(a1,a3);
        float2 ib3 = make_float2(-sgn*b3.y, sgn*b3.x);
        v[q+0]  = cadd(b0,b2);
        v[q+8]  = csub(b0,b2);
        v[q+4]  = cadd(b1,ib3);
        v[q+12] = csub(b1,ib3);
    }
}

// v[k] *= e^{i*k*ang}, incremental powers.
__device__ __forceinline__ void twiddle16(float2 v[16], float ang) {
    float sn, cs; __sincosf(ang, &sn, &cs);
    float2 w = make_float2(cs, sn), t = w;
    v[1] = cmul(v[1], t);
    #pragma unroll
    for (int k = 2; k < 16; ++k) { t = cmul(t, w); v[k] = cmul(v[k], t); }
}

// Stockham radix-16, 3 stages, single 32KB buffer, 4 barriers (R2-proven).
// Input: v[r] = x[tid + 256r]. Output: v[k] = X[tid + 256k].
template<int SIGN>
__device__ void fft4096_r16(float2 v[16], float2* lds, int tid) {
    dft16<SIGN>(v);
    twiddle16(v, (float)SIGN * 2.0f * PI_F * (float)tid / 4096.0f);
    #pragma unroll
    for (int k = 0; k < 16; ++k) lds[SW(16*tid + k)] = v[k];
    __syncthreads();
    #pragma unroll
    for (int r = 0; r < 16; ++r) v[r] = lds[SW(tid + 256*r)];
    dft16<SIGN>(v);
    twiddle16(v, (float)SIGN * 2.0f * PI_F * (float)(tid >> 4) / 256.0f);
    __syncthreads();                       // in-place: all reads before any write
    {
        const int q = tid & 15, p = tid >> 4;
        #pragma unroll
        for (int k = 0; k < 16; ++k) lds[SW(q + 256*p + 16*k)] = v[k];
    }
    __syncthreads();
    #pragma unroll
    for (int r = 0; r < 16; ++r) v[r] = lds[SW(tid + 256*r)];
    dft16<SIGN>(v);
    __syncthreads();                       // lds reusable by caller
}

// ---- Kernel A: precompute Hf (64 rows), Gf (64 rows), Xf (128 rows) ----
__global__ __launch_bounds__(NT, 2) void ldr_pre_k(
    const float* __restrict__ x, const float* __restrict__ G, const float* __restrict__ H,
    float2* __restrict__ Hf, float2* __restrict__ Gf, float2* __restrict__ Xf)
{
    __shared__ float2 lds[NFFT];
    const int tid = threadIdx.x;
    const int bid = blockIdx.x;
    float2 v[16];
    if (bid < 64) {
        const float* h = H + (size_t)bid * NFFT;
        float sn, cs; __sincosf(PI_F * (float)tid / (float)NFFT, &sn, &cs);
        float2 d = make_float2(cs, sn);
        const float2 dstep = make_float2(0.980785280403230449f, 0.195090322016128268f); // e^{i*pi/16}
        #pragma unroll
        for (int k = 0; k < 16; ++k) {
            float hv = h[tid + 256*k];
            v[k] = make_float2(d.x*hv, d.y*hv);
            d = cmul(d, dstep);
        }
        fft4096_r16<-1>(v, lds, tid);
        float2* o = Hf + (size_t)bid * NFFT;
        #pragma unroll
        for (int k = 0; k < 16; ++k) o[tid + 256*k] = v[k];
    } else if (bid < 128) {
        const int row = bid - 64;
        const float* g = G + (size_t)row * NFFT;
        #pragma unroll
        for (int k = 0; k < 16; ++k) v[k] = make_float2(g[tid + 256*k], 0.0f);
        fft4096_r16<-1>(v, lds, tid);
        float2* o = Gf + (size_t)row * NFFT;
        #pragma unroll
        for (int k = 0; k < 16; ++k) o[tid + 256*k] = v[k];
    } else {
        const int row = bid - 128;
        const float* xp = x + (size_t)row * NFFT;
        float sn, cs; __sincosf(PI_F * (float)tid / (float)NFFT, &sn, &cs);
        float2 d = make_float2(cs, -sn);                                                 // conj(D)
        const float2 dstep = make_float2(0.980785280403230449f, -0.195090322016128268f);
        #pragma unroll
        for (int k = 0; k < 16; ++k) {
            float xv = xp[tid + 256*k];
            v[k] = make_float2(d.x*xv, d.y*xv);
            d = cmul(d, dstep);
        }
        fft4096_r16<1>(v, lds, tid);
        const float invn = 1.0f / (float)NFFT;
        float2* o = Xf + (size_t)row * NFFT;
        #pragma unroll
        for (int k = 0; k < 16; ++k) o[tid + 256*k] = make_float2(v[k].x*invn, v[k].y*invn);
    }
}

// ---- Kernel B: middle. grid 2048 = ij(16) x s(4) x b(32); one rank-unit
// per wg, TWO forward FFTs only. Y = Gf . fft(D . fft(Hf . Xf)) is
// conjugate-symmetric (real time-domain partial), so store only k=0..2047
// with Nyquist Y[2048].x packed into element 0's .y (Y[0] and Y[2048] are
// exactly real).  Ph row = ((i*RANK+s)*COUT + j)*BATCH + b, 2048 float2/row.
__global__ __launch_bounds__(NT, 2) void ldr_mid_k(
    const float2* __restrict__ Hf, const float2* __restrict__ Xf,
    const float2* __restrict__ Gf, float2* __restrict__ Ph)
{
    __shared__ float2 lds[NFFT];
    const int tid = threadIdx.x;
    const int bid = blockIdx.x;
    const int b   = bid & (BATCH - 1);
    const int is_ = bid >> 5;           // ij*RANK + s  (row index into Hf/Gf)
    const int s   = is_ & 3;
    const int ij  = is_ >> 2;
    const int i   = ij >> 2;            // COUT = 4
    const int j   = ij & 3;
    const float2* xrow = Xf + (size_t)(i*BATCH + b) * NFFT;
    const float2* hrow = Hf + (size_t)is_ * NFFT;
    const float2* grow = Gf + (size_t)is_ * NFFT;

    float2 v[16];
    #pragma unroll
    for (int k = 0; k < 16; ++k) {
        const int e = tid + 256*k;
        v[k] = cmul(hrow[e], xrow[e]);
    }
    fft4096_r16<-1>(v, lds, tid);
    // multiply by D in registers: elem e = tid + 256k, D_e = e^{i*pi*e/N}
    {
        float sn, cs; __sincosf(PI_F * (float)tid / (float)NFFT, &sn, &cs);
        float2 d = make_float2(cs, sn);
        const float2 dstep = make_float2(0.980785280403230449f, 0.195090322016128268f);
        #pragma unroll
        for (int k = 0; k < 16; ++k) { v[k] = cmul(v[k], d); d = cmul(d, dstep); }
    }
    fft4096_r16<-1>(v, lds, tid);
    // Y[e] = Gf[e] * v[e]; store lower half only (e = tid + 256k, k<8).
    const int u = i * RANK + s;         // plane in [0,16)
    float2* prow = Ph + (size_t)((u*COUT + j)*BATCH + b) * (NFFT/2);
    float2 y0 = cmul(grow[tid], v[0]);
    if (tid == 0) {
        const float2 ynyq = cmul(grow[2048], v[8]);   // e = 2048 (tid=0,k=8)
        y0 = make_float2(y0.x, ynyq.x);               // pack DC.x / Nyq.x
    }
    prow[tid] = y0;
    #pragma unroll
    for (int k = 1; k < 8; ++k) {
        const int e = tid + 256*k;
        prow[e] = cmul(grow[e], v[k]);
    }
}

// ---- Kernel C: final. grid 128 = (j,b). Sum 16 half-rows, mirror the upper
// half by conjugate symmetry, one inverse FFT, write real output / N.
__global__ __launch_bounds__(NT, 2) void ldr_fin_k(
    const float2* __restrict__ Ph, float* __restrict__ out)
{
    __shared__ float2 lds[NFFT];
    __shared__ float2 sh[NFFT/2];      // summed half-spectrum (packed elem 0)
    const int tid = threadIdx.x;
    const int bid = blockIdx.x;        // j*BATCH + b
    const int b = bid & (BATCH - 1);
    const int j = bid >> 5;

    float2 a[8];
    #pragma unroll
    for (int k = 0; k < 8; ++k) a[k] = make_float2(0.0f, 0.0f);
    #pragma unroll
    for (int u = 0; u < 16; ++u) {
        const float2* row = Ph + (size_t)((u*COUT + j)*BATCH + b) * (NFFT/2);
        #pragma unroll
        for (int k = 0; k < 8; ++k) a[k] = cadd(a[k], row[tid + 256*k]);
    }
    #pragma unroll
    for (int k = 0; k < 8; ++k) sh[tid + 256*k] = a[k];
    __syncthreads();

    const float dc  = sh[0].x;         // broadcast reads
    const float nyq = sh[0].y;
    float2 v[16];
    #pragma unroll
    for (int k = 0; k < 8; ++k) v[k] = a[k];
    if (tid == 0) v[0] = make_float2(dc, 0.0f);
    #pragma unroll
    for (int k = 8; k < 16; ++k) {
        const int m = 4096 - (tid + 256*k);          // mirror index in [1,2048]
        if (m == 2048) {                              // only tid==0, k==8
            v[k] = make_float2(nyq, 0.0f);
        } else {
            float2 c = sh[m];
            v[k] = make_float2(c.x, -c.y);            // conj
        }
    }
    // no barrier needed: fft writes lds[], sh[] untouched
    fft4096_r16<1>(v, lds, tid);
    const float invn = 1.0f / (float)NFFT;
    float* orow = out + (size_t)bid * NFFT;
    #pragma unroll
    for (int k = 0; k < 16; ++k) orow[tid + 256*k] = v[k].x * invn;
}

extern "C" void kernel_launch(void* const* d_in, const int* in_sizes, int n_in,
                              void* d_out, int out_size, void* d_ws, size_t ws_size,
                              hipStream_t stream) {
    const float* x = (const float*)d_in[0];   // (CIN, B, N)
    const float* G = (const float*)d_in[1];   // (CIN, COUT, R, N)
    const float* H = (const float*)d_in[2];   // (CIN, COUT, R, N)
    float* out = (float*)d_out;               // (COUT, B, N)

    float2* Hf = (float2*)d_ws;                     // 64 rows  (2 MB)
    float2* Gf = Hf + (size_t)64 * NFFT;            // 64 rows  (2 MB)
    float2* Xf = Gf + (size_t)64 * NFFT;            // 128 rows (4 MB)
    float2* Ph = Xf + (size_t)128 * NFFT;           // 2048 half-rows x 2048 c64 (32 MB)

    ldr_pre_k<<<256, NT, 0, stream>>>(x, G, H, Hf, Gf, Xf);
    ldr_mid_k<<<CIN * COUT * RANK * BATCH, NT, 0, stream>>>(Hf, Xf, Gf, Ph);
    ldr_fin_k<<<COUT * BATCH, NT, 0, stream>>>(Ph, out);
}